// Round 11
// baseline (85.747 us; speedup 1.0000x reference)
//
#include <hip/hip_runtime.h>
#include <hip/hip_bf16.h>

#define NV 512
#define NF 64

typedef __attribute__((ext_vector_type(8))) short bf16x8;
typedef __attribute__((ext_vector_type(4))) float f32x4;

union BF8 { bf16x8 v; unsigned u[4]; };

__device__ __forceinline__ unsigned short f2bf(float x) {
    unsigned u = __float_as_uint(x);
    unsigned r = (u + 0x7fffu + ((u >> 16) & 1u)) >> 16;
    return (unsigned short)r;
}

// AwT byte address: row f (1KB each); XOR-swz mixes f bits 0-2 and 3-5.
__device__ __forceinline__ unsigned awt_addr(int f, int jbyte) {
    return (unsigned)((f * 1024 + jbyte) ^ (((f ^ (f >> 3)) & 7) << 4));
}
// wT (transposed weights) in LDS (fused fallback only).
__device__ __forceinline__ unsigned wt_addr(int m, int n, int kbyte) {
    return (unsigned)(m * 8192 + ((n * 128 + kbyte) ^ (((n ^ (n >> 3)) & 7) << 4)));
}
// scr slot: slot>>1 distinct over write groups {r,r+4,r+8,r+12} (bank-block law:
// a 32B region's bank block depends only on slot>>1), 2-uniform over 16 rows.
__device__ __forceinline__ int slot2(int row) {
    return 2 * (((row >> 2) ^ row) & 3) + (row & 1);
}

__global__ void k_edges(const int* __restrict__ ei, int E, unsigned int* __restrict__ mask) {
    int e = blockIdx.x * 256 + threadIdx.x;
    if (e < E) {
        int s = ei[e];       // src
        int d = ei[E + e];   // dst
        atomicOr(&mask[d * 16 + (s >> 5)], 1u << (s & 31));
    }
}

// 4 waves per v: wave g scans mask words 4g..4g+3; LDS reduce.
__global__ void k_S(const unsigned int* __restrict__ mask, const float* __restrict__ alpha,
                    float* __restrict__ S) {
    __shared__ float red[4][64];
    int v = blockIdx.x;
    int lane = threadIdx.x & 63;
    int g = threadIdx.x >> 6;
    float a0 = 0.f, a1 = 0.f;
    for (int wd = g * 4; wd < g * 4 + 4; ++wd) {
        unsigned bits = mask[v * 16 + wd];
        while (bits) {
            int b0 = __ffs(bits) - 1; bits &= bits - 1;
            float x0 = alpha[((size_t)v * NV + wd * 32 + b0) * NF + lane];
            if (bits) {
                int b1 = __ffs(bits) - 1; bits &= bits - 1;
                a1 += alpha[((size_t)v * NV + wd * 32 + b1) * NF + lane];
            }
            a0 += x0;
        }
    }
    red[g][lane] = a0 + a1;
    __syncthreads();
    if (g == 0)
        S[v * NF + lane] = red[0][lane] + red[1][lane] + red[2][lane] + red[3][lane];
}

// ======================= split path: k_pre + k_mlp =======================
// k_pre: per block w, pre[w][v][f] = (adj GEMM + S + ceps*rv) in bf16.
// LDS 64KB: AwT; first 16KB reused post-GEMM as per-wave scr.
__global__ __launch_bounds__(512, 4) void k_pre(
    const float* __restrict__ alpha, const float* __restrict__ eps_p,
    const unsigned int* __restrict__ mask, const float* __restrict__ S,
    char* __restrict__ preb)
{
    extern __shared__ char smem[];

    const int w    = blockIdx.x;
    const int t    = threadIdx.x;
    const int lane = t & 63;
    const int wid  = t >> 6;
    const int nlo  = lane & 15;
    const int g    = lane >> 4;
    const int mbase = wid * 64;
    const float* src = alpha + (size_t)w * (NV * NF);

    auto stage_half = [&](int i) {
        int task = i * 512 + t;
        int jb = task >> 4;
        int fq = task & 15;
        unsigned ua[4][4];
#pragma unroll
        for (int h = 0; h < 4; ++h) {
            f32x4 r0 = *(const f32x4*)(src + (size_t)(jb * 8 + 2 * h) * NF + fq * 4);
            f32x4 r1 = *(const f32x4*)(src + (size_t)(jb * 8 + 2 * h + 1) * NF + fq * 4);
#pragma unroll
            for (int c = 0; c < 4; ++c)
                ua[c][h] = (unsigned)f2bf(r0[c]) | ((unsigned)f2bf(r1[c]) << 16);
        }
#pragma unroll
        for (int c = 0; c < 4; ++c) {
            BF8 p;
            p.u[0] = ua[c][0]; p.u[1] = ua[c][1]; p.u[2] = ua[c][2]; p.u[3] = ua[c][3];
            *(bf16x8*)(smem + awt_addr(fq * 4 + c, jb * 16)) = p.v;
        }
    };

    f32x4 acc[4][4];
    stage_half(0);
    // init acc from S (C-in of first MFMA)
#pragma unroll
    for (int mi = 0; mi < 4; ++mi)
#pragma unroll
        for (int nt = 0; nt < 4; ++nt)
#pragma unroll
            for (int r = 0; r < 4; ++r)
                acc[mi][nt][r] = S[(size_t)(mbase + mi * 16 + g * 4 + r) * NF + nt * 16 + nlo];

    __syncthreads();

    auto gemm_q = [&](int kq) {
        unsigned qw[4][4];
#pragma unroll
        for (int mi = 0; mi < 4; ++mi) {
            const uint4 q = *(const uint4*)(mask + (size_t)(mbase + mi * 16 + nlo) * 16 + kq * 4);
            qw[mi][0] = q.x; qw[mi][1] = q.y; qw[mi][2] = q.z; qw[mi][3] = q.w;
        }
#pragma unroll
        for (int kr = 0; kr < 4; ++kr) {
            const int kk = kq * 4 + kr;
            BF8 afr[4];
#pragma unroll
            for (int mi = 0; mi < 4; ++mi) {
                unsigned byteb = (qw[mi][kr] >> (g * 8)) & 0xFFu;
#pragma unroll
                for (int h = 0; h < 4; ++h) {
                    unsigned b0 = (byteb >> (2 * h)) & 1u;
                    unsigned b1 = (byteb >> (2 * h + 1)) & 1u;
                    afr[mi].u[h] = (b0 ? 0x3F80u : 0u) | (b1 ? 0x3F800000u : 0u);
                }
            }
#pragma unroll
            for (int nt = 0; nt < 4; ++nt) {
                bf16x8 bfr = *(const bf16x8*)(smem + awt_addr(nt * 16 + nlo, kk * 64 + g * 16));
#pragma unroll
                for (int mi = 0; mi < 4; ++mi)
                    acc[mi][nt] = __builtin_amdgcn_mfma_f32_16x16x32_bf16(afr[mi].v, bfr, acc[mi][nt], 0, 0, 0);
            }
        }
    };

    stage_half(1);
    gemm_q(0);
    gemm_q(1);
    __syncthreads();
    gemm_q(2);
    gemm_q(3);
    __syncthreads();          // AwT dead; reuse [0,16K) as scr

    const float ceps = 1.0f + eps_p[0];
    char* myscr = smem + wid * 2048;           // [16][64] bf16, slot2 swz
    char* dstw  = preb + (size_t)w * 65536;    // pre[w][v][f] bf16

#pragma unroll
    for (int mi = 0; mi < 4; ++mi) {
        int v0 = mbase + mi * 16;
        float rvv[4][4];
#pragma unroll
        for (int nt = 0; nt < 4; ++nt)
#pragma unroll
            for (int r = 0; r < 4; ++r)
                rvv[nt][r] = alpha[((size_t)(v0 + g * 4 + r) * NV + w) * NF + nt * 16 + nlo];

#pragma unroll
        for (int nt = 0; nt < 4; ++nt)
#pragma unroll
            for (int r = 0; r < 4; ++r) {
                float pre = acc[mi][nt][r] + ceps * rvv[nt][r];
                int row = g * 4 + r;
                *(unsigned short*)(myscr + row * 128 + ((2 * (nt * 16 + nlo)) ^ (slot2(row) << 4))) = f2bf(pre);
            }

        // contiguous 16B stores: 2 iters cover the 2KB tile
#pragma unroll
        for (int it = 0; it < 2; ++it) {
            int lin = it * 64 + lane;
            int row = lin >> 3, ch = lin & 7;
            bf16x8 vv = *(const bf16x8*)(myscr + row * 128 + ((ch * 16) ^ (slot2(row) << 4)));
            *(bf16x8*)(dstw + (size_t)(v0 + row) * 128 + ch * 16) = vv;
        }
    }
}

// k_mlp: 1024 blocks x 256 thr; block (w, vh) streams 256 rows of pre through the MLP.
__global__ __launch_bounds__(256, 4) void k_mlp(
    const char* __restrict__ preb, const float* __restrict__ w1, const float* __restrict__ b1,
    const float* __restrict__ w2, const float* __restrict__ b2, float* __restrict__ out)
{
    __shared__ char scr[4][2048];
    const int b    = blockIdx.x;
    const int w    = b >> 1;
    const int vh   = b & 1;
    const int t    = threadIdx.x;
    const int lane = t & 63;
    const int wid  = t >> 6;
    const int nlo  = lane & 15;
    const int g    = lane >> 4;
    const int kbase = g * 8;

    // weight B-frags: phi k = ks*32 + g*8 + e, n = nt*16 + nlo
    bf16x8 w1f[2][4], w2f[2][4];
#pragma unroll
    for (int ks = 0; ks < 2; ++ks)
#pragma unroll
        for (int nt = 0; nt < 4; ++nt) {
            bf16x8 a, bb;
#pragma unroll
            for (int e = 0; e < 8; ++e) {
                int k = ks * 32 + kbase + e;
                a[e]  = (short)f2bf(w1[k * NF + nt * 16 + nlo]);
                bb[e] = (short)f2bf(w2[k * NF + nt * 16 + nlo]);
            }
            w1f[ks][nt] = a;
            w2f[ks][nt] = bb;
        }
    float b1v[4], b2v[4];
#pragma unroll
    for (int nt = 0; nt < 4; ++nt) {
        b1v[nt] = b1[nt * 16 + nlo];
        b2v[nt] = b2[nt * 16 + nlo];
    }

    const char* srcw = preb + (size_t)w * 65536 + (size_t)vh * 32768;
    char* myscr = scr[wid];

#pragma unroll
    for (int mi = 0; mi < 4; ++mi) {
        int rl0 = wid * 64 + mi * 16;          // local row in this half (0..255)

        // layer 1: A-frags direct from global pre (L2/L3-hot)
        bf16x8 a0 = *(const bf16x8*)(srcw + (size_t)(rl0 + nlo) * 128 + g * 16);
        bf16x8 a1 = *(const bf16x8*)(srcw + (size_t)(rl0 + nlo) * 128 + 64 + g * 16);
        f32x4 accm[4];
#pragma unroll
        for (int nt = 0; nt < 4; ++nt) {
            f32x4 z = {0.f, 0.f, 0.f, 0.f};
            z = __builtin_amdgcn_mfma_f32_16x16x32_bf16(a0, w1f[0][nt], z, 0, 0, 0);
            z = __builtin_amdgcn_mfma_f32_16x16x32_bf16(a1, w1f[1][nt], z, 0, 0, 0);
            accm[nt] = z;
        }

        // relu + b1 -> scr (slot2 swz)
#pragma unroll
        for (int nt = 0; nt < 4; ++nt)
#pragma unroll
            for (int r = 0; r < 4; ++r) {
                float hv = accm[nt][r] + b1v[nt];
                hv = hv > 0.f ? hv : 0.f;
                int row = g * 4 + r;
                *(unsigned short*)(myscr + row * 128 + ((2 * (nt * 16 + nlo)) ^ (slot2(row) << 4))) = f2bf(hv);
            }

        // layer 2
        bf16x8 h0 = *(const bf16x8*)(myscr + nlo * 128 + ((g * 16) ^ (slot2(nlo) << 4)));
        bf16x8 h1 = *(const bf16x8*)(myscr + nlo * 128 + ((g * 16 + 64) ^ (slot2(nlo) << 4)));
#pragma unroll
        for (int nt = 0; nt < 4; ++nt) {
            f32x4 z = {0.f, 0.f, 0.f, 0.f};
            z = __builtin_amdgcn_mfma_f32_16x16x32_bf16(h0, w2f[0][nt], z, 0, 0, 0);
            z = __builtin_amdgcn_mfma_f32_16x16x32_bf16(h1, w2f[1][nt], z, 0, 0, 0);
#pragma unroll
            for (int r = 0; r < 4; ++r) {
                int v = vh * 256 + rl0 + g * 4 + r;
                out[((size_t)v * NV + w) * NF + nt * 16 + nlo] = z[r] + b2v[nt];
            }
        }
    }
}

// ======================= fused fallback (R10 + slot2, no prefetch) =======================
__global__ __launch_bounds__(512, 4) void k_main(
    const float* __restrict__ alpha, const float* __restrict__ w1, const float* __restrict__ b1,
    const float* __restrict__ w2, const float* __restrict__ b2, const float* __restrict__ eps_p,
    const unsigned int* __restrict__ mask, const float* __restrict__ S,
    float* __restrict__ out)
{
    extern __shared__ char smem[];
    const int w    = blockIdx.x;
    const int t    = threadIdx.x;
    const int lane = t & 63;
    const int wid  = t >> 6;
    const int nlo  = lane & 15;
    const int g    = lane >> 4;
    const int mbase = wid * 64;
    const float* src = alpha + (size_t)w * (NV * NF);

    auto stage_half = [&](int i) {
        int task = i * 512 + t;
        int jb = task >> 4;
        int fq = task & 15;
        unsigned ua[4][4];
#pragma unroll
        for (int h = 0; h < 4; ++h) {
            f32x4 r0 = *(const f32x4*)(src + (size_t)(jb * 8 + 2 * h) * NF + fq * 4);
            f32x4 r1 = *(const f32x4*)(src + (size_t)(jb * 8 + 2 * h + 1) * NF + fq * 4);
#pragma unroll
            for (int c = 0; c < 4; ++c)
                ua[c][h] = (unsigned)f2bf(r0[c]) | ((unsigned)f2bf(r1[c]) << 16);
        }
#pragma unroll
        for (int c = 0; c < 4; ++c) {
            BF8 p;
            p.u[0] = ua[c][0]; p.u[1] = ua[c][1]; p.u[2] = ua[c][2]; p.u[3] = ua[c][3];
            *(bf16x8*)(smem + awt_addr(fq * 4 + c, jb * 16)) = p.v;
        }
    };

    f32x4 acc[4][4];
    stage_half(0);
#pragma unroll
    for (int mi = 0; mi < 4; ++mi)
#pragma unroll
        for (int nt = 0; nt < 4; ++nt)
#pragma unroll
            for (int r = 0; r < 4; ++r)
                acc[mi][nt][r] = S[(size_t)(mbase + mi * 16 + g * 4 + r) * NF + nt * 16 + nlo];
    __syncthreads();

    auto gemm_q = [&](int kq) {
        unsigned qw[4][4];
#pragma unroll
        for (int mi = 0; mi < 4; ++mi) {
            const uint4 q = *(const uint4*)(mask + (size_t)(mbase + mi * 16 + nlo) * 16 + kq * 4);
            qw[mi][0] = q.x; qw[mi][1] = q.y; qw[mi][2] = q.z; qw[mi][3] = q.w;
        }
#pragma unroll
        for (int kr = 0; kr < 4; ++kr) {
            const int kk = kq * 4 + kr;
            BF8 afr[4];
#pragma unroll
            for (int mi = 0; mi < 4; ++mi) {
                unsigned byteb = (qw[mi][kr] >> (g * 8)) & 0xFFu;
#pragma unroll
                for (int h = 0; h < 4; ++h) {
                    unsigned b0 = (byteb >> (2 * h)) & 1u;
                    unsigned b1 = (byteb >> (2 * h + 1)) & 1u;
                    afr[mi].u[h] = (b0 ? 0x3F80u : 0u) | (b1 ? 0x3F800000u : 0u);
                }
            }
#pragma unroll
            for (int nt = 0; nt < 4; ++nt) {
                bf16x8 bfr = *(const bf16x8*)(smem + awt_addr(nt * 16 + nlo, kk * 64 + g * 16));
#pragma unroll
                for (int mi = 0; mi < 4; ++mi)
                    acc[mi][nt] = __builtin_amdgcn_mfma_f32_16x16x32_bf16(afr[mi].v, bfr, acc[mi][nt], 0, 0, 0);
            }
        }
    };

    stage_half(1);
    gemm_q(0); gemm_q(1);
    __syncthreads();
    gemm_q(2); gemm_q(3);
    __syncthreads();

    if (t < 256) {
        int m  = t >> 7;
        int sub = t & 127;
        int jb = sub >> 4;
        int fq = sub & 15;
        const float* wsrc = m ? w2 : w1;
        unsigned ua[4][4];
#pragma unroll
        for (int h = 0; h < 4; ++h) {
            f32x4 r0 = *(const f32x4*)(wsrc + (size_t)(jb * 8 + 2 * h) * NF + fq * 4);
            f32x4 r1 = *(const f32x4*)(wsrc + (size_t)(jb * 8 + 2 * h + 1) * NF + fq * 4);
#pragma unroll
            for (int c = 0; c < 4; ++c)
                ua[c][h] = (unsigned)f2bf(r0[c]) | ((unsigned)f2bf(r1[c]) << 16);
        }
#pragma unroll
        for (int c = 0; c < 4; ++c) {
            BF8 p;
            p.u[0] = ua[c][0]; p.u[1] = ua[c][1]; p.u[2] = ua[c][2]; p.u[3] = ua[c][3];
            *(bf16x8*)(smem + wt_addr(m, fq * 4 + c, jb * 16)) = p.v;
        }
    }
    float b1v[4], b2v[4];
#pragma unroll
    for (int nt = 0; nt < 4; ++nt) {
        b1v[nt] = b1[nt * 16 + nlo];
        b2v[nt] = b2[nt * 16 + nlo];
    }
    const float ceps = 1.0f + eps_p[0];
    __syncthreads();

    char* myscr = smem + 16384 + wid * 2048;
#pragma unroll
    for (int mi = 0; mi < 4; ++mi) {
        int v0 = mbase + mi * 16;
        float rvv[4][4];
#pragma unroll
        for (int nt = 0; nt < 4; ++nt)
#pragma unroll
            for (int r = 0; r < 4; ++r)
                rvv[nt][r] = alpha[((size_t)(v0 + g * 4 + r) * NV + w) * NF + nt * 16 + nlo];
#pragma unroll
        for (int nt = 0; nt < 4; ++nt)
#pragma unroll
            for (int r = 0; r < 4; ++r) {
                float pre = acc[mi][nt][r] + ceps * rvv[nt][r];
                int row = g * 4 + r;
                *(unsigned short*)(myscr + row * 128 + ((2 * (nt * 16 + nlo)) ^ (slot2(row) << 4))) = f2bf(pre);
            }
        bf16x8 a0 = *(const bf16x8*)(myscr + nlo * 128 + ((g * 16) ^ (slot2(nlo) << 4)));
        bf16x8 a1 = *(const bf16x8*)(myscr + nlo * 128 + ((g * 16 + 64) ^ (slot2(nlo) << 4)));
        f32x4 accm[4];
#pragma unroll
        for (int nt = 0; nt < 4; ++nt) {
            bf16x8 wf0 = *(const bf16x8*)(smem + wt_addr(0, nt * 16 + nlo, g * 16));
            bf16x8 wf1 = *(const bf16x8*)(smem + wt_addr(0, nt * 16 + nlo, 64 + g * 16));
            f32x4 z = {0.f, 0.f, 0.f, 0.f};
            z = __builtin_amdgcn_mfma_f32_16x16x32_bf16(a0, wf0, z, 0, 0, 0);
            z = __builtin_amdgcn_mfma_f32_16x16x32_bf16(a1, wf1, z, 0, 0, 0);
            accm[nt] = z;
        }
#pragma unroll
        for (int nt = 0; nt < 4; ++nt)
#pragma unroll
            for (int r = 0; r < 4; ++r) {
                float hv = accm[nt][r] + b1v[nt];
                hv = hv > 0.f ? hv : 0.f;
                int row = g * 4 + r;
                *(unsigned short*)(myscr + row * 128 + ((2 * (nt * 16 + nlo)) ^ (slot2(row) << 4))) = f2bf(hv);
            }
        bf16x8 h0 = *(const bf16x8*)(myscr + nlo * 128 + ((g * 16) ^ (slot2(nlo) << 4)));
        bf16x8 h1 = *(const bf16x8*)(myscr + nlo * 128 + ((g * 16 + 64) ^ (slot2(nlo) << 4)));
#pragma unroll
        for (int nt = 0; nt < 4; ++nt) {
            bf16x8 wf0 = *(const bf16x8*)(smem + wt_addr(1, nt * 16 + nlo, g * 16));
            bf16x8 wf1 = *(const bf16x8*)(smem + wt_addr(1, nt * 16 + nlo, 64 + g * 16));
            f32x4 z = {0.f, 0.f, 0.f, 0.f};
            z = __builtin_amdgcn_mfma_f32_16x16x32_bf16(h0, wf0, z, 0, 0, 0);
            z = __builtin_amdgcn_mfma_f32_16x16x32_bf16(h1, wf1, z, 0, 0, 0);
#pragma unroll
            for (int r = 0; r < 4; ++r) {
                int vv = v0 + g * 4 + r;
                out[((size_t)vv * NV + w) * NF + nt * 16 + nlo] = z[r] + b2v[nt];
            }
        }
    }
}

extern "C" void kernel_launch(void* const* d_in, const int* in_sizes, int n_in,
                              void* d_out, int out_size, void* d_ws, size_t ws_size,
                              hipStream_t stream) {
    const float* alpha = (const float*)d_in[0];
    const int*   ei    = (const int*)d_in[1];
    const float* w1    = (const float*)d_in[2];
    const float* b1    = (const float*)d_in[3];
    const float* w2    = (const float*)d_in[4];
    const float* b2    = (const float*)d_in[5];
    const float* eps   = (const float*)d_in[6];
    float* out = (float*)d_out;
    int E = in_sizes[1] / 2;

    // ws layout (bytes): mask[32768] | S[131072] | pre[33554432]
    unsigned int* mask = (unsigned int*)d_ws;
    float* S = (float*)((char*)d_ws + 32768);
    char*  preb = (char*)d_ws + 163840;
    const size_t need = 163840 + (size_t)NV * 65536;

    hipMemsetAsync(mask, 0, 32768, stream);
    k_edges<<<(E + 255) / 256, 256, 0, stream>>>(ei, E, mask);
    k_S    <<<NV, 256, 0, stream>>>(mask, alpha, S);

    if (ws_size >= need) {
        hipFuncSetAttribute(reinterpret_cast<const void*>(k_pre),
                            hipFuncAttributeMaxDynamicSharedMemorySize, 65536);
        k_pre<<<NV, 512, 65536, stream>>>(alpha, eps, mask, S, preb);
        k_mlp<<<NV * 2, 256, 0, stream>>>(preb, w1, b1, w2, b2, out);
    } else {
        hipFuncSetAttribute(reinterpret_cast<const void*>(k_main),
                            hipFuncAttributeMaxDynamicSharedMemorySize, 65536);
        k_main<<<NV, 512, 65536, stream>>>(alpha, w1, b1, w2, b2, eps, mask, S, out);
    }
}

// Round 12
// 63.463 us; speedup vs baseline: 1.3511x; 1.3511x over previous
//
#include <hip/hip_runtime.h>
#include <hip/hip_bf16.h>

#define NV 512
#define NF 64

typedef __attribute__((ext_vector_type(8))) short bf16x8;
typedef __attribute__((ext_vector_type(4))) float f32x4;

union BF8 { bf16x8 v; unsigned u[4]; };

__device__ __forceinline__ unsigned short f2bf(float x) {
    unsigned u = __float_as_uint(x);
    unsigned r = (u + 0x7fffu + ((u >> 16) & 1u)) >> 16;
    return (unsigned short)r;
}

// AwT byte address: row f (1KB each); XOR-swz mixes f bits 0-2 and 3-5.
__device__ __forceinline__ unsigned awt_addr(int f, int jbyte) {
    return (unsigned)((f * 1024 + jbyte) ^ (((f ^ (f >> 3)) & 7) << 4));
}
// wT (transposed weights) in LDS.
__device__ __forceinline__ unsigned wt_addr(int m, int n, int kbyte) {
    return (unsigned)(m * 8192 + ((n * 128 + kbyte) ^ (((n ^ (n >> 3)) & 7) << 4)));
}
// scr slot: slot>>1 distinct over write groups {r,r+4,r+8,r+12}; 2-uniform overall.
__device__ __forceinline__ int slot2(int row) {
    return 2 * (((row >> 2) ^ row) & 3) + (row & 1);
}

__global__ void k_edges(const int* __restrict__ ei, int E, unsigned int* __restrict__ mask) {
    int e = blockIdx.x * 256 + threadIdx.x;
    if (e < E) {
        int s = ei[e];       // src
        int d = ei[E + e];   // dst
        atomicOr(&mask[d * 16 + (s >> 5)], 1u << (s & 31));
    }
}

// 4 waves per v: wave g scans mask words 4g..4g+3; LDS reduce.
__global__ void k_S(const unsigned int* __restrict__ mask, const float* __restrict__ alpha,
                    float* __restrict__ S) {
    __shared__ float red[4][64];
    int v = blockIdx.x;
    int lane = threadIdx.x & 63;
    int g = threadIdx.x >> 6;
    float a0 = 0.f, a1 = 0.f;
    for (int wd = g * 4; wd < g * 4 + 4; ++wd) {
        unsigned bits = mask[v * 16 + wd];
        while (bits) {
            int b0 = __ffs(bits) - 1; bits &= bits - 1;
            float x0 = alpha[((size_t)v * NV + wd * 32 + b0) * NF + lane];
            if (bits) {
                int b1 = __ffs(bits) - 1; bits &= bits - 1;
                a1 += alpha[((size_t)v * NV + wd * 32 + b1) * NF + lane];
            }
            a0 += x0;
        }
    }
    red[g][lane] = a0 + a1;
    __syncthreads();
    if (g == 0)
        S[v * NF + lane] = red[0][lane] + red[1][lane] + red[2][lane] + red[3][lane];
}

// LDS 64KB: AwT bf16 [64 f][512 j] swizzled (GEMM phase); post-GEMM reuse:
//   [0, 16K)   w1T/w2T
//   [16K, 32K) scr bf16 per-wave [16 rows][64], 2KB/wave, slot2 swz
// launch_bounds (512, 2): 256 unified regs/wave (~192 arch + 64 acc), 1 block/CU.
// R3 vs R10 showed 1 vs 2 blocks/CU is perf-neutral; the register headroom is
// the point (deep load hoisting / MFMA pipelining was impossible at 64 arch regs).
__global__ __launch_bounds__(512, 2) void k_main(
    const float* __restrict__ alpha, const float* __restrict__ w1, const float* __restrict__ b1,
    const float* __restrict__ w2, const float* __restrict__ b2, const float* __restrict__ eps_p,
    const unsigned int* __restrict__ mask, const float* __restrict__ S,
    float* __restrict__ out)
{
    extern __shared__ char smem[];
    const int w    = blockIdx.x;
    const int t    = threadIdx.x;
    const int lane = t & 63;
    const int wid  = t >> 6;
    const int nlo  = lane & 15;
    const int g    = lane >> 4;
    const int mbase = wid * 64;
    const float* src = alpha + (size_t)w * (NV * NF);

    auto stage_half = [&](int i) {
        int task = i * 512 + t;
        int jb = task >> 4;
        int fq = task & 15;
        unsigned ua[4][4];
#pragma unroll
        for (int h = 0; h < 4; ++h) {
            f32x4 r0 = *(const f32x4*)(src + (size_t)(jb * 8 + 2 * h) * NF + fq * 4);
            f32x4 r1 = *(const f32x4*)(src + (size_t)(jb * 8 + 2 * h + 1) * NF + fq * 4);
#pragma unroll
            for (int c = 0; c < 4; ++c)
                ua[c][h] = (unsigned)f2bf(r0[c]) | ((unsigned)f2bf(r1[c]) << 16);
        }
#pragma unroll
        for (int c = 0; c < 4; ++c) {
            BF8 p;
            p.u[0] = ua[c][0]; p.u[1] = ua[c][1]; p.u[2] = ua[c][2]; p.u[3] = ua[c][3];
            *(bf16x8*)(smem + awt_addr(fq * 4 + c, jb * 16)) = p.v;
        }
    };

    f32x4 acc[4][4];

    // phase 1a: stage half0 (HBM loads first)
    stage_half(0);

    // phase 1b: preload ALL mask words for this wave's 4 m-tiles (64 regs, L2);
    // they cover the entire GEMM so no loads remain inside the MFMA loops.
    uint4 qm[4][4];   // [mi][kq]
#pragma unroll
    for (int mi = 0; mi < 4; ++mi)
#pragma unroll
        for (int kq = 0; kq < 4; ++kq)
            qm[mi][kq] = *(const uint4*)(mask + (size_t)(mbase + mi * 16 + nlo) * 16 + kq * 4);

    // phase 1c: init acc from S (C-in of first MFMA)
#pragma unroll
    for (int mi = 0; mi < 4; ++mi)
#pragma unroll
        for (int nt = 0; nt < 4; ++nt)
#pragma unroll
            for (int r = 0; r < 4; ++r)
                acc[mi][nt][r] = S[(size_t)(mbase + mi * 16 + g * 4 + r) * NF + nt * 16 + nlo];

    __syncthreads();

    auto gemm_q = [&](int kq) {
#pragma unroll
        for (int kr = 0; kr < 4; ++kr) {
            const int kk = kq * 4 + kr;
            const unsigned wv[4] = {
                (&qm[0][kq].x)[kr], (&qm[1][kq].x)[kr],
                (&qm[2][kq].x)[kr], (&qm[3][kq].x)[kr] };
            BF8 afr[4];
#pragma unroll
            for (int mi = 0; mi < 4; ++mi) {
                unsigned byteb = (wv[mi] >> (g * 8)) & 0xFFu;
#pragma unroll
                for (int h = 0; h < 4; ++h) {
                    unsigned b0 = (byteb >> (2 * h)) & 1u;
                    unsigned b1 = (byteb >> (2 * h + 1)) & 1u;
                    afr[mi].u[h] = (b0 ? 0x3F80u : 0u) | (b1 ? 0x3F800000u : 0u);
                }
            }
#pragma unroll
            for (int nt = 0; nt < 4; ++nt) {
                bf16x8 bfr = *(const bf16x8*)(smem + awt_addr(nt * 16 + nlo, kk * 64 + g * 16));
#pragma unroll
                for (int mi = 0; mi < 4; ++mi)
                    acc[mi][nt] = __builtin_amdgcn_mfma_f32_16x16x32_bf16(afr[mi].v, bfr, acc[mi][nt], 0, 0, 0);
            }
        }
    };

    // pipeline: {stage half1 || GEMM kq0-1 (half0 only)} | barrier | GEMM kq2-3
    stage_half(1);
    gemm_q(0); gemm_q(1);
    __syncthreads();
    gemm_q(2); gemm_q(3);
    __syncthreads();          // AwT dead; reuse for wT + scr

    if (t < 256) {
        int m  = t >> 7;
        int sub = t & 127;
        int jb = sub >> 4;
        int fq = sub & 15;
        const float* wsrc = m ? w2 : w1;
        unsigned ua[4][4];
#pragma unroll
        for (int h = 0; h < 4; ++h) {
            f32x4 r0 = *(const f32x4*)(wsrc + (size_t)(jb * 8 + 2 * h) * NF + fq * 4);
            f32x4 r1 = *(const f32x4*)(wsrc + (size_t)(jb * 8 + 2 * h + 1) * NF + fq * 4);
#pragma unroll
            for (int c = 0; c < 4; ++c)
                ua[c][h] = (unsigned)f2bf(r0[c]) | ((unsigned)f2bf(r1[c]) << 16);
        }
#pragma unroll
        for (int c = 0; c < 4; ++c) {
            BF8 p;
            p.u[0] = ua[c][0]; p.u[1] = ua[c][1]; p.u[2] = ua[c][2]; p.u[3] = ua[c][3];
            *(bf16x8*)(smem + wt_addr(m, fq * 4 + c, jb * 16)) = p.v;
        }
    }
    float b1v[4], b2v[4];
#pragma unroll
    for (int nt = 0; nt < 4; ++nt) {
        b1v[nt] = b1[nt * 16 + nlo];
        b2v[nt] = b2[nt * 16 + nlo];
    }
    const float ceps = 1.0f + eps_p[0];
    __syncthreads();

    char* myscr = smem + 16384 + wid * 2048;
#pragma unroll
    for (int mi = 0; mi < 4; ++mi) {
        int v0 = mbase + mi * 16;
        float rvv[4][4];
#pragma unroll
        for (int nt = 0; nt < 4; ++nt)
#pragma unroll
            for (int r = 0; r < 4; ++r)
                rvv[nt][r] = alpha[((size_t)(v0 + g * 4 + r) * NV + w) * NF + nt * 16 + nlo];
#pragma unroll
        for (int nt = 0; nt < 4; ++nt)
#pragma unroll
            for (int r = 0; r < 4; ++r) {
                float pre = acc[mi][nt][r] + ceps * rvv[nt][r];
                int row = g * 4 + r;
                *(unsigned short*)(myscr + row * 128 + ((2 * (nt * 16 + nlo)) ^ (slot2(row) << 4))) = f2bf(pre);
            }
        bf16x8 a0 = *(const bf16x8*)(myscr + nlo * 128 + ((g * 16) ^ (slot2(nlo) << 4)));
        bf16x8 a1 = *(const bf16x8*)(myscr + nlo * 128 + ((g * 16 + 64) ^ (slot2(nlo) << 4)));
        f32x4 accm[4];
#pragma unroll
        for (int nt = 0; nt < 4; ++nt) {
            bf16x8 wf0 = *(const bf16x8*)(smem + wt_addr(0, nt * 16 + nlo, g * 16));
            bf16x8 wf1 = *(const bf16x8*)(smem + wt_addr(0, nt * 16 + nlo, 64 + g * 16));
            f32x4 z = {0.f, 0.f, 0.f, 0.f};
            z = __builtin_amdgcn_mfma_f32_16x16x32_bf16(a0, wf0, z, 0, 0, 0);
            z = __builtin_amdgcn_mfma_f32_16x16x32_bf16(a1, wf1, z, 0, 0, 0);
            accm[nt] = z;
        }
#pragma unroll
        for (int nt = 0; nt < 4; ++nt)
#pragma unroll
            for (int r = 0; r < 4; ++r) {
                float hv = accm[nt][r] + b1v[nt];
                hv = hv > 0.f ? hv : 0.f;
                int row = g * 4 + r;
                *(unsigned short*)(myscr + row * 128 + ((2 * (nt * 16 + nlo)) ^ (slot2(row) << 4))) = f2bf(hv);
            }
        bf16x8 h0 = *(const bf16x8*)(myscr + nlo * 128 + ((g * 16) ^ (slot2(nlo) << 4)));
        bf16x8 h1 = *(const bf16x8*)(myscr + nlo * 128 + ((g * 16 + 64) ^ (slot2(nlo) << 4)));
#pragma unroll
        for (int nt = 0; nt < 4; ++nt) {
            bf16x8 wf0 = *(const bf16x8*)(smem + wt_addr(1, nt * 16 + nlo, g * 16));
            bf16x8 wf1 = *(const bf16x8*)(smem + wt_addr(1, nt * 16 + nlo, 64 + g * 16));
            f32x4 z = {0.f, 0.f, 0.f, 0.f};
            z = __builtin_amdgcn_mfma_f32_16x16x32_bf16(h0, wf0, z, 0, 0, 0);
            z = __builtin_amdgcn_mfma_f32_16x16x32_bf16(h1, wf1, z, 0, 0, 0);
#pragma unroll
            for (int r = 0; r < 4; ++r) {
                int vv = v0 + g * 4 + r;
                out[((size_t)vv * NV + w) * NF + nt * 16 + nlo] = z[r] + b2v[nt];
            }
        }
    }
}

extern "C" void kernel_launch(void* const* d_in, const int* in_sizes, int n_in,
                              void* d_out, int out_size, void* d_ws, size_t ws_size,
                              hipStream_t stream) {
    const float* alpha = (const float*)d_in[0];
    const int*   ei    = (const int*)d_in[1];
    const float* w1    = (const float*)d_in[2];
    const float* b1    = (const float*)d_in[3];
    const float* w2    = (const float*)d_in[4];
    const float* b2    = (const float*)d_in[5];
    const float* eps   = (const float*)d_in[6];
    float* out = (float*)d_out;
    int E = in_sizes[1] / 2;

    // ws layout (bytes): mask[32768] | S[131072]
    unsigned int* mask = (unsigned int*)d_ws;
    float* S = (float*)((char*)d_ws + 32768);

    hipMemsetAsync(mask, 0, 32768, stream);
    k_edges<<<(E + 255) / 256, 256, 0, stream>>>(ei, E, mask);
    k_S    <<<NV, 256, 0, stream>>>(mask, alpha, S);

    hipFuncSetAttribute(reinterpret_cast<const void*>(k_main),
                        hipFuncAttributeMaxDynamicSharedMemorySize, 65536);
    k_main<<<NV, 512, 65536, stream>>>(alpha, w1, b1, w2, b2, eps, mask, S, out);
}